// Round 1
// baseline (513.664 us; speedup 1.0000x reference)
//
#include <hip/hip_runtime.h>
#include <math.h>

#define THREADS 256
#define D 128

__global__ void k_zero(int* __restrict__ p, int n) {
    int i = blockIdx.x * blockDim.x + threadIdx.x;
    if (i < n) p[i] = 0;
}

// deg[d] += 1 for each edge destination (self-loop handled analytically as +1)
__global__ void k_degree(const int* __restrict__ dst, int* __restrict__ deg, int E) {
    int i = blockIdx.x * blockDim.x + threadIdx.x;
    if (i < E) atomicAdd(&deg[dst[i]], 1);
}

__global__ void k_dinv(const int* __restrict__ deg, float* __restrict__ dinv, int N) {
    int i = blockIdx.x * blockDim.x + threadIdx.x;
    if (i < N) dinv[i] = rsqrtf((float)(deg[i] + 1));
}

// W12 = W1 @ W2  (128x2),  cvec = b1^T @ W2 (2)
__global__ void k_w12(const float* __restrict__ W1, const float* __restrict__ W2,
                      const float* __restrict__ b1, float* __restrict__ W12,
                      float* __restrict__ cvec) {
    int t = threadIdx.x;          // 256 threads
    int k = t >> 1, c = t & 1;
    float acc = 0.f;
    for (int m = 0; m < D; ++m) acc += W1[k * D + m] * W2[m * 2 + c];
    W12[k * 2 + c] = acc;
    if (t < 2) {
        float s = 0.f;
        for (int m = 0; m < D; ++m) s += b1[m] * W2[m * 2 + t];
        cvec[t] = s;
    }
}

// z = x @ W12 (one wave per node row); also initialize a1 and srow with the
// self-loop terms: a1[d] = z[d]*dinv[d]^2, srow[d] = dinv[d]^2.
__global__ void k_z(const float* __restrict__ x, const float* __restrict__ W12,
                    const float* __restrict__ dinv, float* __restrict__ z,
                    float* __restrict__ a1, float* __restrict__ srow, int N) {
    int gid  = blockIdx.x * blockDim.x + threadIdx.x;
    int node = gid >> 6;
    int lane = threadIdx.x & 63;
    if (node >= N) return;
    // lane l covers k = 2l, 2l+1
    float2 xv = *(const float2*)(x + (size_t)node * D + lane * 2);
    float4 wv = *(const float4*)(W12 + lane * 4);
    float p0 = xv.x * wv.x + xv.y * wv.z;
    float p1 = xv.x * wv.y + xv.y * wv.w;
#pragma unroll
    for (int o = 32; o > 0; o >>= 1) {
        p0 += __shfl_xor(p0, o);
        p1 += __shfl_xor(p1, o);
    }
    if (lane == 0) {
        float w = dinv[node], w2 = w * w;
        z[node * 2 + 0] = p0;
        z[node * 2 + 1] = p1;
        a1[node * 2 + 0] = p0 * w2;
        a1[node * 2 + 1] = p1 * w2;
        srow[node] = w2;
    }
}

// Pass A: a1[d] += dinv[s]*dinv[d] * z[s];  srow[d] += dinv[s]*dinv[d]
__global__ void k_scatterA(const int* __restrict__ src, const int* __restrict__ dst,
                           const float* __restrict__ dinv, const float* __restrict__ z,
                           float* __restrict__ a1, float* __restrict__ srow, int E) {
    int e = blockIdx.x * blockDim.x + threadIdx.x;
    if (e >= E) return;
    int s = src[e], d = dst[e];
    float w = dinv[s] * dinv[d];
    float z0 = z[s * 2 + 0], z1 = z[s * 2 + 1];
    atomicAdd(&a1[d * 2 + 0], w * z0);
    atomicAdd(&a1[d * 2 + 1], w * z1);
    atomicAdd(&srow[d], w);
}

// init pass B accumulator with self-loop term: l2[d] = a1[d]*dinv[d]^2
__global__ void k_initB(const float* __restrict__ a1, const float* __restrict__ dinv,
                        float* __restrict__ l2, int N) {
    int i = blockIdx.x * blockDim.x + threadIdx.x;
    if (i >= N) return;
    float w2 = dinv[i] * dinv[i];
    l2[i * 2 + 0] = a1[i * 2 + 0] * w2;
    l2[i * 2 + 1] = a1[i * 2 + 1] * w2;
}

// Pass B: l2[d] += dinv[s]*dinv[d] * a1[s]
__global__ void k_scatterB(const int* __restrict__ src, const int* __restrict__ dst,
                           const float* __restrict__ dinv, const float* __restrict__ a1,
                           float* __restrict__ l2, int E) {
    int e = blockIdx.x * blockDim.x + threadIdx.x;
    if (e >= E) return;
    int s = src[e], d = dst[e];
    float w = dinv[s] * dinv[d];
    atomicAdd(&l2[d * 2 + 0], w * a1[s * 2 + 0]);
    atomicAdd(&l2[d * 2 + 1], w * a1[s * 2 + 1]);
}

// logits = l2 + srow*cvec + b2 ; gumbel-softmax epilogue
__global__ void k_final(const float* __restrict__ l2, const float* __restrict__ srow,
                        const float* __restrict__ cvec, const float* __restrict__ b2,
                        const float* __restrict__ noise, float* __restrict__ out, int N) {
    int i = blockIdx.x * blockDim.x + threadIdx.x;
    if (i >= N) return;
    const float EPS = 1e-9f;
    float sr = srow[i];
    float c0 = cvec[0], c1 = cvec[1];
    float g0 = -logf(-logf(noise[i * 2 + 0] + EPS) + EPS);
    float g1 = -logf(-logf(noise[i * 2 + 1] + EPS) + EPS);
    float u0 = (l2[i * 2 + 0] + sr * c0 + b2[0] + g0) * 2.0f;  // /0.5
    float u1 = (l2[i * 2 + 1] + sr * c1 + b2[1] + g1) * 2.0f;
    float m = fmaxf(u0, u1);
    float e0 = __expf(u0 - m), e1 = __expf(u1 - m);
    float inv = 1.0f / (e0 + e1);
    out[i * 2 + 0] = e0 * inv;
    out[i * 2 + 1] = e1 * inv;
}

extern "C" void kernel_launch(void* const* d_in, const int* in_sizes, int n_in,
                              void* d_out, int out_size, void* d_ws, size_t ws_size,
                              hipStream_t stream) {
    const float* x     = (const float*)d_in[0];
    const int*   ei    = (const int*)d_in[1];
    const float* W1    = (const float*)d_in[2];
    const float* b1    = (const float*)d_in[3];
    const float* W2    = (const float*)d_in[4];
    const float* b2    = (const float*)d_in[5];
    const float* noise = (const float*)d_in[6];
    float* out = (float*)d_out;

    const int N = in_sizes[0] / D;
    const int E = in_sizes[1] / 2;
    const int* src = ei;
    const int* dst = ei + E;

    // workspace carve (all chunks 16B-multiple sized)
    char* p = (char*)d_ws;
    int*   deg  = (int*)p;   p += (size_t)N * 4;
    float* dinv = (float*)p; p += (size_t)N * 4;
    float* z    = (float*)p; p += (size_t)N * 8;
    float* a1   = (float*)p; p += (size_t)N * 8;
    float* srow = (float*)p; p += (size_t)N * 4;
    float* l2   = (float*)p; p += (size_t)N * 8;
    float* W12  = (float*)p; p += 256 * 4;
    float* cvec = (float*)p; p += 16;

    int gN = (N + THREADS - 1) / THREADS;
    int gE = (E + THREADS - 1) / THREADS;
    int gZ = (N + 3) / 4;  // one wave (64 lanes) per node, 4 waves per block

    k_zero<<<gN, THREADS, 0, stream>>>(deg, N);
    k_degree<<<gE, THREADS, 0, stream>>>(dst, deg, E);
    k_dinv<<<gN, THREADS, 0, stream>>>(deg, dinv, N);
    k_w12<<<1, THREADS, 0, stream>>>(W1, W2, b1, W12, cvec);
    k_z<<<gZ, THREADS, 0, stream>>>(x, W12, dinv, z, a1, srow, N);
    k_scatterA<<<gE, THREADS, 0, stream>>>(src, dst, dinv, z, a1, srow, E);
    k_initB<<<gN, THREADS, 0, stream>>>(a1, dinv, l2, N);
    k_scatterB<<<gE, THREADS, 0, stream>>>(src, dst, dinv, a1, l2, E);
    k_final<<<gN, THREADS, 0, stream>>>(l2, srow, cvec, b2, noise, out, N);
}

// Round 2
// 160.150 us; speedup vs baseline: 3.2074x; 3.2074x over previous
//
#include <hip/hip_runtime.h>
#include <math.h>

#define THREADS 256
#define D 128

__global__ void k_zero(int* __restrict__ p, int n) {
    int i = blockIdx.x * blockDim.x + threadIdx.x;
    if (i < n) p[i] = 0;
}

// rank[e] = old count; deg[d] accumulates in-degree (self-loop added analytically)
__global__ void k_degree_rank(const int* __restrict__ dst, int* __restrict__ deg,
                              int* __restrict__ rank, int E) {
    int e = blockIdx.x * blockDim.x + threadIdx.x;
    if (e < E) rank[e] = atomicAdd(&deg[dst[e]], 1);
}

__global__ void k_dinv(const int* __restrict__ deg, float* __restrict__ dinv, int N) {
    int i = blockIdx.x * blockDim.x + threadIdx.x;
    if (i < N) dinv[i] = rsqrtf((float)(deg[i] + 1));
}

// ---- exclusive scan of deg -> rowstart (3 kernels) ----
__global__ void k_scan1(const int* __restrict__ deg, int* __restrict__ partial, int N) {
    __shared__ int s[256];
    int t = threadIdx.x;
    int i = blockIdx.x * 256 + t;
    s[t] = (i < N) ? deg[i] : 0;
    __syncthreads();
    for (int o = 128; o > 0; o >>= 1) {
        if (t < o) s[t] += s[t + o];
        __syncthreads();
    }
    if (t == 0) partial[blockIdx.x] = s[0];
}

__global__ void k_scan2(int* __restrict__ partial, int nb) {
    __shared__ int s[1024];
    int t = threadIdx.x;
    int v = (t < nb) ? partial[t] : 0;
    int orig = v;
    s[t] = v;
    __syncthreads();
    for (int o = 1; o < 1024; o <<= 1) {
        int add = (t >= o) ? s[t - o] : 0;
        __syncthreads();
        s[t] += add;
        __syncthreads();
    }
    if (t < nb) partial[t] = s[t] - orig;  // exclusive
}

__global__ void k_scan3(const int* __restrict__ deg, const int* __restrict__ partial,
                        int* __restrict__ rowstart, int N) {
    __shared__ int s[256];
    int t = threadIdx.x;
    int i = blockIdx.x * 256 + t;
    int v = (i < N) ? deg[i] : 0;
    int orig = v;
    s[t] = v;
    __syncthreads();
    for (int o = 1; o < 256; o <<= 1) {
        int add = (t >= o) ? s[t - o] : 0;
        __syncthreads();
        s[t] += add;
        __syncthreads();
    }
    if (i < N) rowstart[i] = partial[blockIdx.x] + s[t] - orig;
}

// csr[rowstart[dst]+rank] = src  — no atomics
__global__ void k_fill(const int* __restrict__ src, const int* __restrict__ dst,
                       const int* __restrict__ rank, const int* __restrict__ rowstart,
                       int* __restrict__ csr, int E) {
    int e = blockIdx.x * blockDim.x + threadIdx.x;
    if (e < E) csr[rowstart[dst[e]] + rank[e]] = src[e];
}

// W12 = W1 @ W2  (128x2),  cvec = b1^T @ W2 (2)
__global__ void k_w12(const float* __restrict__ W1, const float* __restrict__ W2,
                      const float* __restrict__ b1, float* __restrict__ W12,
                      float* __restrict__ cvec) {
    int t = threadIdx.x;
    int k = t >> 1, c = t & 1;
    float acc = 0.f;
    for (int m = 0; m < D; ++m) acc += W1[k * D + m] * W2[m * 2 + c];
    W12[k * 2 + c] = acc;
    if (t < 2) {
        float s = 0.f;
        for (int m = 0; m < D; ++m) s += b1[m] * W2[m * 2 + t];
        cvec[t] = s;
    }
}

// z = x @ W12 (one wave per node row)
__global__ void k_z(const float* __restrict__ x, const float* __restrict__ W12,
                    float2* __restrict__ z, int N) {
    int gid  = blockIdx.x * blockDim.x + threadIdx.x;
    int node = gid >> 6;
    int lane = threadIdx.x & 63;
    if (node >= N) return;
    float2 xv = *(const float2*)(x + (size_t)node * D + lane * 2);
    float4 wv = *(const float4*)(W12 + lane * 4);
    float p0 = xv.x * wv.x + xv.y * wv.z;
    float p1 = xv.x * wv.y + xv.y * wv.w;
#pragma unroll
    for (int o = 32; o > 0; o >>= 1) {
        p0 += __shfl_xor(p0, o);
        p1 += __shfl_xor(p1, o);
    }
    if (lane == 0) {
        float2 r; r.x = p0; r.y = p1;
        z[node] = r;
    }
}

// Pass A (gather): a1[d] = dinv[d]*sum_s dinv[s]*z[s] + dinv[d]^2*z[d]
//                  srow[d] = dinv[d]*sum_s dinv[s] + dinv[d]^2
__global__ void k_gatherA(const int* __restrict__ csr, const int* __restrict__ rowstart,
                          const int* __restrict__ deg, const float* __restrict__ dinv,
                          const float2* __restrict__ z, float2* __restrict__ a1,
                          float* __restrict__ srow, int N) {
    int g = blockIdx.x * blockDim.x + threadIdx.x;
    int node = g >> 4;
    int lane = threadIdx.x & 15;
    if (node >= N) return;
    int rs = rowstart[node], dg = deg[node];
    float acc0 = 0.f, acc1 = 0.f, sw = 0.f;
    for (int j = lane; j < dg; j += 16) {
        int s = csr[rs + j];
        float w = dinv[s];
        float2 zv = z[s];
        acc0 += w * zv.x; acc1 += w * zv.y; sw += w;
    }
#pragma unroll
    for (int o = 8; o > 0; o >>= 1) {
        acc0 += __shfl_xor(acc0, o);
        acc1 += __shfl_xor(acc1, o);
        sw   += __shfl_xor(sw, o);
    }
    if (lane == 0) {
        float wd = dinv[node], wd2 = wd * wd;
        float2 zv = z[node];
        float2 r;
        r.x = wd * acc0 + wd2 * zv.x;
        r.y = wd * acc1 + wd2 * zv.y;
        a1[node] = r;
        srow[node] = wd * sw + wd2;
    }
}

// Pass B (gather) + rank-1 bias + gumbel softmax epilogue, fused
__global__ void k_gatherB(const int* __restrict__ csr, const int* __restrict__ rowstart,
                          const int* __restrict__ deg, const float* __restrict__ dinv,
                          const float2* __restrict__ a1, const float* __restrict__ srow,
                          const float* __restrict__ cvec, const float* __restrict__ b2,
                          const float2* __restrict__ noise, float2* __restrict__ out, int N) {
    int g = blockIdx.x * blockDim.x + threadIdx.x;
    int node = g >> 4;
    int lane = threadIdx.x & 15;
    if (node >= N) return;
    int rs = rowstart[node], dg = deg[node];
    float acc0 = 0.f, acc1 = 0.f;
    for (int j = lane; j < dg; j += 16) {
        int s = csr[rs + j];
        float w = dinv[s];
        float2 av = a1[s];
        acc0 += w * av.x; acc1 += w * av.y;
    }
#pragma unroll
    for (int o = 8; o > 0; o >>= 1) {
        acc0 += __shfl_xor(acc0, o);
        acc1 += __shfl_xor(acc1, o);
    }
    if (lane == 0) {
        const float EPS = 1e-9f;
        float wd = dinv[node], wd2 = wd * wd;
        float2 av = a1[node];
        float sr = srow[node];
        float l0 = wd * acc0 + wd2 * av.x + sr * cvec[0] + b2[0];
        float l1 = wd * acc1 + wd2 * av.y + sr * cvec[1] + b2[1];
        float2 nv = noise[node];
        float g0 = -logf(-logf(nv.x + EPS) + EPS);
        float g1 = -logf(-logf(nv.y + EPS) + EPS);
        float u0 = (l0 + g0) * 2.0f;
        float u1 = (l1 + g1) * 2.0f;
        float m = fmaxf(u0, u1);
        float e0 = __expf(u0 - m), e1 = __expf(u1 - m);
        float inv = 1.0f / (e0 + e1);
        float2 r; r.x = e0 * inv; r.y = e1 * inv;
        out[node] = r;
    }
}

extern "C" void kernel_launch(void* const* d_in, const int* in_sizes, int n_in,
                              void* d_out, int out_size, void* d_ws, size_t ws_size,
                              hipStream_t stream) {
    const float* x     = (const float*)d_in[0];
    const int*   ei    = (const int*)d_in[1];
    const float* W1    = (const float*)d_in[2];
    const float* b1    = (const float*)d_in[3];
    const float* W2    = (const float*)d_in[4];
    const float* b2    = (const float*)d_in[5];
    const float* noise = (const float*)d_in[6];
    float* out = (float*)d_out;

    const int N = in_sizes[0] / D;
    const int E = in_sizes[1] / 2;
    const int* src = ei;
    const int* dst = ei + E;

    // workspace carve
    char* p = (char*)d_ws;
    int*   deg      = (int*)p;   p += (size_t)N * 4;
    float* dinv     = (float*)p; p += (size_t)N * 4;
    int*   rowstart = (int*)p;   p += (size_t)N * 4;
    float* z        = (float*)p; p += (size_t)N * 8;
    float* a1       = (float*)p; p += (size_t)N * 8;
    float* srow     = (float*)p; p += (size_t)N * 4;
    int*   rank     = (int*)p;   p += (size_t)E * 4;
    int*   csr      = (int*)p;   p += (size_t)E * 4;
    int*   partial  = (int*)p;   p += 4096;
    float* W12      = (float*)p; p += 256 * 4;
    float* cvec     = (float*)p; p += 16;

    int gN  = (N + THREADS - 1) / THREADS;
    int gE  = (E + THREADS - 1) / THREADS;
    int gZ  = (N + 3) / 4;        // 64 lanes/node, 4 nodes/block
    int g16 = (N * 16 + THREADS - 1) / THREADS;  // 16 lanes/node
    int nb  = (N + 255) / 256;    // scan blocks (196 <= 1024)

    k_zero<<<gN, THREADS, 0, stream>>>(deg, N);
    k_degree_rank<<<gE, THREADS, 0, stream>>>(dst, deg, rank, E);
    k_dinv<<<gN, THREADS, 0, stream>>>(deg, dinv, N);
    k_scan1<<<nb, 256, 0, stream>>>(deg, partial, N);
    k_scan2<<<1, 1024, 0, stream>>>(partial, nb);
    k_scan3<<<nb, 256, 0, stream>>>(deg, partial, rowstart, N);
    k_fill<<<gE, THREADS, 0, stream>>>(src, dst, rank, rowstart, csr, E);
    k_w12<<<1, THREADS, 0, stream>>>(W1, W2, b1, W12, cvec);
    k_z<<<gZ, THREADS, 0, stream>>>(x, W12, (float2*)z, N);
    k_gatherA<<<g16, THREADS, 0, stream>>>(csr, rowstart, deg, dinv, (const float2*)z,
                                           (float2*)a1, srow, N);
    k_gatherB<<<g16, THREADS, 0, stream>>>(csr, rowstart, deg, dinv, (const float2*)a1,
                                           srow, cvec, b2, (const float2*)noise,
                                           (float2*)out, N);
}